// Round 2
// baseline (440.079 us; speedup 1.0000x reference)
//
#include <hip/hip_runtime.h>
#include <stdint.h>

// ExpertLoRA: E=8,H=2048,D=2048,F=1024,T=2048,K=4,R=8, SCALING=2, LIMIT=7, alpha=1.702
// Pipeline:
//  k_route   : w[E][T], per-expert token lists, per-token (e,slot) hit list
//  k_prefix  : prefix-sum + compact WORKLIST of live (e,my,nx) GEMM blocks,
//              expert-interleaved so block b -> XCD b%8 -> expert b%8 (L2 affinity)
//  k_wprep   : W1eff^T = (W1 + 2*A1@B1)^T -> bf16 [E][D][H]; same for W2eff^T [E][H][F]
//  k_xconv   : X fp32 -> bf16 [T][H]
//  k_gemm8p  : 256^2 8-phase counted-vmcnt MFMA GEMM (T2 swizzle + T3/T4 + T5),
//              flat 256-block grid, each block loops worklist items (load balance:
//              old (8,8,8) grid paired live blocks on half the CUs -> 2x serialization)
//  k_combine : out[t,h] = sum_j wt_j * (pairbuf[pair_j][h] + b2[e_j][h])
// ws layout: pairbuf ALIASES W1T (dead after gemm1).

typedef short bf16x8 __attribute__((ext_vector_type(8)));
typedef float f32x4 __attribute__((ext_vector_type(4)));

__device__ __forceinline__ short bf16r(float f) {
  uint32_t u = __float_as_uint(f);
  u += 0x7fffu + ((u >> 16) & 1u);
  return (short)(u >> 16);
}

__device__ __forceinline__ float bf16f(short s) {
  uint32_t u = ((uint32_t)(uint16_t)s) << 16;
  return __uint_as_float(u);
}

__device__ __forceinline__ void load_lds16(const void* g, void* l) {
  __builtin_amdgcn_global_load_lds((const __attribute__((address_space(1))) void*)g,
                                   (__attribute__((address_space(3))) void*)l,
                                   16, 0, 0);
}

__global__ void k_route(const int* __restrict__ idx_raw, const float* __restrict__ rw,
                        float* __restrict__ w, int* __restrict__ cnt, int* __restrict__ list,
                        int* __restrict__ tok_nh, int* __restrict__ tok_pair) {
  __shared__ int s_nz;
  const int tid = threadIdx.x;
  if (tid == 0) s_nz = 0;
  __syncthreads();
  int found = 0;
  for (int i = tid; i < 4096; i += 256) found |= idx_raw[2 * i + 1];
  if (found) atomicOr(&s_nz, 1);
  __syncthreads();
  const bool is64 = (s_nz == 0);

  const int t = blockIdx.x * 256 + tid;  // grid = 8 x 256
  int ek[4]; float rk[4];
#pragma unroll
  for (int k = 0; k < 4; k++) {
    ek[k] = is64 ? idx_raw[2 * (t * 4 + k)] : idx_raw[t * 4 + k];
    rk[k] = rw[t * 4 + k];
  }
  int j = 0;
#pragma unroll
  for (int e = 0; e < 8; e++) {
    float s = 0.f;
#pragma unroll
    for (int k = 0; k < 4; k++) s += (ek[k] == e) ? rk[k] : 0.f;
    w[e * 2048 + t] = s;
    if (s != 0.f) {
      int slot = atomicAdd(&cnt[e], 1);
      list[e * 2048 + slot] = t;
      tok_pair[t * 4 + j] = (e << 16) | slot;
      j++;
    }
  }
  tok_nh[t] = j;
}

// offs[0..8]: prefix sums. offs[9]: #worklist items.
// wl[i] = (e<<6) | (my<<3) | nx, interleaved so wl[j*8+e] belongs to expert e
// (common case: 4 m-blocks x 8 n-blocks x 8 experts = exactly 256 items).
__global__ void k_prefix(const int* __restrict__ cnt, int* __restrict__ offs,
                         int* __restrict__ wl) {
  if (threadIdx.x == 0 && blockIdx.x == 0) {
    int s = 0; int nb[8];
    for (int e = 0; e < 8; e++) {
      offs[e] = s; s += cnt[e];
      nb[e] = (cnt[e] + 255) >> 8;
    }
    offs[8] = s;
    int p = 0;
    for (int j = 0; j < 64; j++)       // j = my*8 + nx
      for (int e = 0; e < 8; e++)
        if (j < nb[e] * 8) wl[p++] = (e << 6) | j;
    offs[9] = p;
  }
}

// O[e][n][k] = bf16( W[e][k][n] + 2 * sum_r A[e][k][r]*Bm[e][r][n] )
// 64(k) x 32(n) tile: wave writes 64 consecutive k -> 128B stores.
__global__ void k_wprep(const float* __restrict__ W, const float* __restrict__ A,
                        const float* __restrict__ Bm, short* __restrict__ O,
                        int Kd, int Nd) {
  const int e = blockIdx.z;
  const float* We = W + (size_t)e * Kd * Nd;
  const float* Ae = A + (size_t)e * Kd * 8;
  const float* Be = Bm + (size_t)e * 8 * Nd;
  short* Oe = O + (size_t)e * Kd * Nd;
  __shared__ float tile[64][33];
  __shared__ float As[64][9];
  __shared__ float Bs[8][32];
  const int n0 = blockIdx.x * 32, k0 = blockIdx.y * 64;
  const int tx = threadIdx.x & 31, ty = threadIdx.x >> 5;  // 32 x 8
#pragma unroll
  for (int i = 0; i < 8; i++)
    tile[ty + 8 * i][tx] = We[(size_t)(k0 + ty + 8 * i) * Nd + n0 + tx];
  {
    int kk = threadIdx.x >> 3, r = threadIdx.x & 7;
    As[kk][r] = Ae[(size_t)(k0 + kk) * 8 + r];
    As[kk + 32][r] = Ae[(size_t)(k0 + kk + 32) * 8 + r];
  }
  {
    int rr = threadIdx.x >> 5, nn = threadIdx.x & 31;
    Bs[rr][nn] = Be[(size_t)rr * Nd + n0 + nn];
  }
  __syncthreads();
  const int kk2 = threadIdx.x & 63, ng = threadIdx.x >> 6;
#pragma unroll
  for (int i = 0; i < 8; i++) {
    int n = ng + 4 * i;
    float v = tile[kk2][n];
    float l = 0.f;
#pragma unroll
    for (int r = 0; r < 8; r++) l += As[kk2][r] * Bs[r][n];
    Oe[(size_t)(n0 + n) * Kd + k0 + kk2] = bf16r(v + 2.0f * l);
  }
}

__global__ void k_xconv(const float* __restrict__ x, short* __restrict__ xb) {
  const int i = (blockIdx.x * 256 + threadIdx.x) * 4;
  float4 v = *(const float4*)(x + i);
  short4 s;
  s.x = bf16r(v.x); s.y = bf16r(v.y); s.z = bf16r(v.z); s.w = bf16r(v.w);
  *(short4*)(xb + i) = s;
}

// ---------------- 256^2 8-phase GEMM (worklist-driven) ----------------
// Tile 256x256, BK=64, 512 threads = 8 waves (2M x 4N), per-wave C = 128x64.
// LDS: sA/sB each [2 slots][256 rows][64 cols] bf16 = 64KB -> 128KB total.
// Swizzle: LDS[row][c16] holds global[row][c16 ^ (row&7)] (16B units).
// Phase p: {ds_read frag group | stage 1 half-tile} ; s_barrier ; lgkmcnt(0) ;
//          setprio(1) ; 16 MFMA ; setprio(0) ; [vmcnt(4) @ ph4/ph8] ; s_barrier.
// Stage map (iter i computes tiles a=2i (slot0, ph1-4), b=2i+1 (slot1, ph5-8)):
//   ph1: b.A0->s1   ph2: b.A1->s1   ph3: (a+2).B0->s0  ph4: (a+2).B1->s0 +GATE
//   ph5: (a+2).A0->s0 ph6: (a+2).A1->s0 ph7: (b+2).B0->s1 ph8: (b+2).B1->s1 +GATE
// Every region's last ds_read drains >=1 barrier before its overwriting stage;
// every staged region is fenced by vmcnt(4)+barrier before first read.
// Across items: epilogue reads only acc regs; next prologue's vmcnt(4) drains
// the 4 stale tail loads as the oldest -> invariant re-established.

#define PH_SYNC() do { \
    asm volatile("s_barrier" ::: "memory"); \
    asm volatile("s_waitcnt lgkmcnt(0)" ::: "memory"); \
    __builtin_amdgcn_sched_barrier(0); \
    __builtin_amdgcn_s_setprio(1); } while (0)
#define PH_END() do { \
    __builtin_amdgcn_s_setprio(0); \
    asm volatile("s_barrier" ::: "memory"); } while (0)
#define PH_END_GATE() do { \
    __builtin_amdgcn_s_setprio(0); \
    asm volatile("s_waitcnt vmcnt(4)" ::: "memory"); \
    asm volatile("s_barrier" ::: "memory"); } while (0)

#define MM(AARR, BARR, MG, NG) \
  _Pragma("unroll") \
  for (int f_ = 0; f_ < 4; ++f_) \
    _Pragma("unroll") \
    for (int g_ = 0; g_ < 2; ++g_) \
      _Pragma("unroll") \
      for (int s_ = 0; s_ < 2; ++s_) \
        acc[(MG) + f_][(NG) + g_] = __builtin_amdgcn_mfma_f32_16x16x32_bf16( \
            AARR[f_][s_], BARR[g_][s_], acc[(MG) + f_][(NG) + g_], 0, 0, 0);

template <int KDIM, bool GATHER, bool GLU>
__global__ __launch_bounds__(512) void k_gemm8p(
    const short* __restrict__ Abuf, const short* __restrict__ Bbuf,
    const float* __restrict__ bias, const int* __restrict__ cnt,
    const int* __restrict__ offs, const int* __restrict__ wl,
    const int* __restrict__ list, short* __restrict__ outbuf) {
  constexpr int KT = KDIM / 64;
  constexpr int NIT = KT / 2;

  __shared__ __align__(16) short sA[2 * 256 * 64];
  __shared__ __align__(16) short sB[2 * 256 * 64];
  constexpr int SLOT = 256 * 64;   // 16384 shorts
  constexpr int HALF = 128 * 64;   // 8192 shorts

  const int tid = threadIdx.x;
  const int lane = tid & 63;
  const int wv = tid >> 6;   // 0..7
  const int wr = wv >> 2;    // 0..1
  const int wc = wv & 3;     // 0..3
  const int lm = lane & 15;
  const int quad = lane >> 4;

  const int srow = tid >> 3;                        // 0..63
  const int scol = ((tid & 7) ^ (srow & 7)) * 8;    // 16B-unit swizzle

  // LDS read addressing (swizzled)
  const int rbA = (wr * 128 + lm) * 64;
  const int rbB = (wc * 64 + lm) * 64;
  const int c0 = ((0 + quad) ^ (lane & 7)) * 8;
  const int c1 = ((4 + quad) ^ (lane & 7)) * 8;

  const int nitems = offs[9];

  for (int item = blockIdx.x; item < nitems; item += 256) {
    const int wit = wl[item];
    const int e = wit >> 6;
    const int m0 = ((wit >> 3) & 7) * 256;
    const int n0 = (wit & 7) * 256;
    const int M = cnt[e];
    const int off_e = offs[e];
    const short* Bp = Bbuf + (size_t)e * 2048 * KDIM;

    // ---- stage source offsets (pre-swizzled global column) ----
    uint32_t offA[4], offB[4];
#pragma unroll
    for (int j = 0; j < 4; ++j) {
      const int r = m0 + srow + 64 * j;
      const int rc = min(r, M - 1);
      if constexpr (GATHER) {
        offA[j] = (uint32_t)list[e * 2048 + rc] * (uint32_t)KDIM + (uint32_t)scol;
      } else {
        offA[j] = (uint32_t)(off_e + rc) * (uint32_t)KDIM + (uint32_t)scol;
      }
      offB[j] = (uint32_t)(n0 + srow + 64 * j) * (uint32_t)KDIM + (uint32_t)scol;
    }

    auto stageA = [&](int slot, int h, int kt) {
      short* d = sA + slot * SLOT + h * HALF + tid * 8;
      load_lds16(Abuf + offA[2 * h] + kt * 64, d);
      load_lds16(Abuf + offA[2 * h + 1] + kt * 64, d + 4096);
    };
    auto stageB = [&](int slot, int h, int kt) {
      short* d = sB + slot * SLOT + h * HALF + tid * 8;
      load_lds16(Bp + offB[2 * h] + kt * 64, d);
      load_lds16(Bp + offB[2 * h + 1] + kt * 64, d + 4096);
    };

    auto rdA = [&](int slot, int mg, bf16x8 (&a)[4][2]) {
#pragma unroll
      for (int f = 0; f < 4; ++f) {
        const short* p = sA + slot * SLOT + rbA + (mg + f) * 1024;
        a[f][0] = *(const bf16x8*)(p + c0);
        a[f][1] = *(const bf16x8*)(p + c1);
      }
    };
    auto rdB = [&](int slot, int ng, bf16x8 (&b)[2][2]) {
#pragma unroll
      for (int g = 0; g < 2; ++g) {
        const short* p = sB + slot * SLOT + rbB + (ng + g) * 1024;
        b[g][0] = *(const bf16x8*)(p + c0);
        b[g][1] = *(const bf16x8*)(p + c1);
      }
    };

    f32x4 acc[8][4];
#pragma unroll
    for (int i = 0; i < 8; ++i)
#pragma unroll
      for (int j = 0; j < 4; ++j) acc[i][j] = (f32x4){0.f, 0.f, 0.f, 0.f};

    // ---- prologue: tile0 full (slot0) + tile1 B halves (slot1) ----
    stageB(0, 0, 0); stageB(0, 1, 0);
    stageA(0, 0, 0); stageA(0, 1, 0);
    {
      const int k1 = (1 < KT - 1) ? 1 : (KT - 1);
      stageB(1, 0, k1); stageB(1, 1, k1);
    }
    asm volatile("s_waitcnt vmcnt(4)" ::: "memory");
    asm volatile("s_barrier" ::: "memory");

    bf16x8 aLo[4][2], aHi[4][2], bLo[2][2], bHi[2][2];

#pragma unroll 1
    for (int it = 0; it < NIT; ++it) {
      const int tb = 2 * it + 1;
      const int tS0 = min(2 * it + 2, KT - 1);
      const int tS1 = min(2 * it + 3, KT - 1);
      // ph1
      rdA(0, 0, aLo); rdB(0, 0, bLo);
      stageA(1, 0, tb);
      PH_SYNC(); MM(aLo, bLo, 0, 0); PH_END();
      // ph2
      rdB(0, 2, bHi);
      stageA(1, 1, tb);
      PH_SYNC(); MM(aLo, bHi, 0, 2); PH_END();
      // ph3
      rdA(0, 4, aHi);
      stageB(0, 0, tS0);
      PH_SYNC(); MM(aHi, bLo, 4, 0); PH_END();
      // ph4
      stageB(0, 1, tS0);
      PH_SYNC(); MM(aHi, bHi, 4, 2); PH_END_GATE();
      // ph5
      rdA(1, 0, aLo); rdB(1, 0, bLo);
      stageA(0, 0, tS0);
      PH_SYNC(); MM(aLo, bLo, 0, 0); PH_END();
      // ph6
      rdB(1, 2, bHi);
      stageA(0, 1, tS0);
      PH_SYNC(); MM(aLo, bHi, 0, 2); PH_END();
      // ph7
      rdA(1, 4, aHi);
      stageB(1, 0, tS1);
      PH_SYNC(); MM(aHi, bLo, 4, 0); PH_END();
      // ph8
      stageB(1, 1, tS1);
      PH_SYNC(); MM(aHi, bHi, 4, 2); PH_END_GATE();
    }

    // ---- epilogue ----
    if constexpr (GLU) {
      const float* be = bias + e * 2048;
#pragma unroll
      for (int m = 0; m < 8; ++m) {
        const int rbase = m0 + wr * 128 + m * 16 + quad * 4;
#pragma unroll
        for (int g = 0; g < 4; ++g) {
          const int col = n0 + wc * 64 + g * 16 + lm;  // parity == lane parity
          const float bb = be[col];
#pragma unroll
          for (int r = 0; r < 4; ++r) {
            const int slot = rbase + r;
            float val = acc[m][g][r] + bb;
            float other = __shfl_xor(val, 1);
            if (((lane & 1) == 0) && (slot < M)) {
              float gt = fminf(val, 7.f);
              float u = fminf(fmaxf(other, -7.f), 7.f);
              float glu = gt / (1.f + __expf(-1.702f * gt));
              outbuf[(size_t)(off_e + slot) * 1024 + (col >> 1)] = bf16r((u + 1.f) * glu);
            }
          }
        }
      }
    } else {
#pragma unroll
      for (int m = 0; m < 8; ++m) {
#pragma unroll
        for (int r = 0; r < 4; ++r) {
          const int slot = m0 + wr * 128 + m * 16 + quad * 4 + r;
          if (slot >= M) continue;
          short* prow = outbuf + (size_t)(off_e + slot) * 2048;
#pragma unroll
          for (int g = 0; g < 4; ++g) {
            const int h = n0 + wc * 64 + g * 16 + lm;
            prow[h] = bf16r(acc[m][g][r]);
          }
        }
      }
    }
  }
}

// out[t,h] = sum_j wt_j * (pairbuf[pair_j][h] + b2[e_j][h])
__global__ __launch_bounds__(256) void k_combine(
    const short* __restrict__ pairbuf, const float* __restrict__ bias2,
    const float* __restrict__ wbuf, const int* __restrict__ offs,
    const int* __restrict__ tok_nh, const int* __restrict__ tok_pair,
    float* __restrict__ out) {
  const int t = blockIdx.x;
  const int h0 = threadIdx.x * 8;
  const int nh = tok_nh[t];
  float acc[8];
#pragma unroll
  for (int i = 0; i < 8; i++) acc[i] = 0.f;
  for (int j = 0; j < nh; j++) {
    const int p = tok_pair[t * 4 + j];
    const int e = p >> 16, slot = p & 0xffff;
    const float wt = wbuf[e * 2048 + t];
    const bf16x8 v = *(const bf16x8*)(pairbuf + (size_t)(offs[e] + slot) * 2048 + h0);
    const float4 bA = *(const float4*)(bias2 + e * 2048 + h0);
    const float4 bB = *(const float4*)(bias2 + e * 2048 + h0 + 4);
    acc[0] += wt * (bf16f(v[0]) + bA.x);
    acc[1] += wt * (bf16f(v[1]) + bA.y);
    acc[2] += wt * (bf16f(v[2]) + bA.z);
    acc[3] += wt * (bf16f(v[3]) + bA.w);
    acc[4] += wt * (bf16f(v[4]) + bB.x);
    acc[5] += wt * (bf16f(v[5]) + bB.y);
    acc[6] += wt * (bf16f(v[6]) + bB.z);
    acc[7] += wt * (bf16f(v[7]) + bB.w);
  }
  float4 oA = {acc[0], acc[1], acc[2], acc[3]};
  float4 oB = {acc[4], acc[5], acc[6], acc[7]};
  *(float4*)(out + (size_t)t * 2048 + h0) = oA;
  *(float4*)(out + (size_t)t * 2048 + h0 + 4) = oB;
}

extern "C" void kernel_launch(void* const* d_in, const int* in_sizes, int n_in,
                              void* d_out, int out_size, void* d_ws, size_t ws_size,
                              hipStream_t stream) {
  const float* x   = (const float*)d_in[0];
  const float* rw  = (const float*)d_in[1];
  const float* w1  = (const float*)d_in[2];
  const float* b1  = (const float*)d_in[3];
  const float* w2  = (const float*)d_in[4];
  const float* b2  = (const float*)d_in[5];
  const float* a1  = (const float*)d_in[6];
  const float* lb1 = (const float*)d_in[7];
  const float* a2  = (const float*)d_in[8];
  const float* lb2 = (const float*)d_in[9];
  const int* idx   = (const int*)d_in[10];
  float* out = (float*)d_out;

  char* ws = (char*)d_ws;
  int* cnt     = (int*)(ws);
  int* offs    = (int*)(ws + 64);
  int* tok_nh  = (int*)(ws + 128);           // 8 KB
  int* wl      = (int*)(ws + 8320);          // 2 KB worklist
  float* wbuf  = (float*)(ws + 16384);       // 64 KB
  int* list    = (int*)(ws + 81920);         // 64 KB
  int* tok_pair= (int*)(ws + 147456);        // 32 KB
  short* Xb    = (short*)(ws + (1ull << 20));        // 8 MB
  short* gated = (short*)(ws + 9437184ull);          // 16 MB
  short* W2T   = (short*)(ws + 26214400ull);         // 32 MB
  short* W1T   = (short*)(ws + 59768832ull);         // 64 MB
  short* pairbuf = (short*)(ws + 59768832ull);       // ALIASES W1T (dead after gemm1)

  hipMemsetAsync(cnt, 0, 64, stream);

  k_route<<<dim3(8), dim3(256), 0, stream>>>(idx, rw, wbuf, cnt, list, tok_nh, tok_pair);
  k_prefix<<<dim3(1), dim3(64), 0, stream>>>(cnt, offs, wl);
  k_wprep<<<dim3(64, 32, 8), dim3(256), 0, stream>>>(w1, a1, lb1, W1T, 2048, 2048);
  k_wprep<<<dim3(64, 16, 8), dim3(256), 0, stream>>>(w2, a2, lb2, W2T, 1024, 2048);
  k_xconv<<<dim3(4096), dim3(256), 0, stream>>>(x, Xb);
  k_gemm8p<2048, true, true><<<dim3(256), dim3(512), 0, stream>>>(
      Xb, W1T, b1, cnt, offs, wl, list, gated);
  k_gemm8p<1024, false, false><<<dim3(256), dim3(512), 0, stream>>>(
      gated, W2T, nullptr, cnt, offs, wl, nullptr, pairbuf);
  k_combine<<<dim3(2048), dim3(256), 0, stream>>>(pairbuf, b2, wbuf, offs, tok_nh, tok_pair, out);
}

// Round 4
// 416.490 us; speedup vs baseline: 1.0566x; 1.0566x over previous
//
#include <hip/hip_runtime.h>
#include <stdint.h>

// ExpertLoRA: E=8,H=2048,D=2048,F=1024,T=2048,K=4,R=8, SCALING=2, LIMIT=7, alpha=1.702
// Pipeline:
//  k_route   : w[E][T], per-expert token lists, per-token (e,slot) hit list
//  k_prefix  : prefix sums + FIXED-LAYOUT worklist wl[j*8+e] (dead=-1), parallel
//  k_wprep   : W1eff^T=(W1+2*A1@B1)^T -> bf16 [E][D][H]; W2eff^T [E][H][F]
//              float4 loads, short8 stores
//  k_xconv   : X fp32 -> bf16 [T][H]
//  k_gemmG   : 256^2 MFMA GEMM, one merged GROUP per K-tile (BK=64):
//              burst 24 ds_reads (compiler emits counted lgkmcnt cascade),
//              early A-stage / mid-barrier / late B-stage, vmcnt(4) gate,
//              2 barriers per K-tile (was 8), s-outermost MFMA order.
//  k_combine : out[t,h] = sum_j wt_j * (pairbuf[pair_j][h] + b2[e_j][h])
// ws layout: pairbuf ALIASES W1T (dead after gemm1).

typedef short bf16x8 __attribute__((ext_vector_type(8)));
typedef float f32x4 __attribute__((ext_vector_type(4)));

__device__ __forceinline__ short bf16r(float f) {
  uint32_t u = __float_as_uint(f);
  u += 0x7fffu + ((u >> 16) & 1u);
  return (short)(u >> 16);
}

__device__ __forceinline__ float bf16f(short s) {
  uint32_t u = ((uint32_t)(uint16_t)s) << 16;
  return __uint_as_float(u);
}

__device__ __forceinline__ void load_lds16(const void* g, void* l) {
  __builtin_amdgcn_global_load_lds((const __attribute__((address_space(1))) void*)g,
                                   (__attribute__((address_space(3))) void*)l,
                                   16, 0, 0);
}

__global__ void k_route(const int* __restrict__ idx_raw, const float* __restrict__ rw,
                        float* __restrict__ w, int* __restrict__ cnt, int* __restrict__ list,
                        int* __restrict__ tok_nh, int* __restrict__ tok_pair) {
  __shared__ int s_nz;
  const int tid = threadIdx.x;
  if (tid == 0) s_nz = 0;
  __syncthreads();
  int found = 0;
  for (int i = tid; i < 4096; i += 256) found |= idx_raw[2 * i + 1];
  if (found) atomicOr(&s_nz, 1);
  __syncthreads();
  const bool is64 = (s_nz == 0);

  const int t = blockIdx.x * 256 + tid;  // grid = 8 x 256
  int ek[4]; float rk[4];
#pragma unroll
  for (int k = 0; k < 4; k++) {
    ek[k] = is64 ? idx_raw[2 * (t * 4 + k)] : idx_raw[t * 4 + k];
    rk[k] = rw[t * 4 + k];
  }
  int j = 0;
#pragma unroll
  for (int e = 0; e < 8; e++) {
    float s = 0.f;
#pragma unroll
    for (int k = 0; k < 4; k++) s += (ek[k] == e) ? rk[k] : 0.f;
    w[e * 2048 + t] = s;
    if (s != 0.f) {
      int slot = atomicAdd(&cnt[e], 1);
      list[e * 2048 + slot] = t;
      tok_pair[t * 4 + j] = (e << 16) | slot;
      j++;
    }
  }
  tok_nh[t] = j;
}

// offs[0..8]: prefix sums. wl: FIXED 512 slots, wl[j*8+e] = (e<<6)|j if live
// (j < nb_e*8) else -1. Common case (all nb_e=4): slots 0..255 live.
__global__ void k_prefix(const int* __restrict__ cnt, int* __restrict__ offs,
                         int* __restrict__ wl) {
  const int tid = threadIdx.x;  // 512
  __shared__ int sc[8];
  if (tid < 8) sc[tid] = cnt[tid];
  __syncthreads();
  if (tid == 0) {
    int s = 0;
    for (int e = 0; e < 8; e++) { offs[e] = s; s += sc[e]; }
    offs[8] = s;
  }
  const int j = tid >> 3, e = tid & 7;
  const int nb = (sc[e] + 255) >> 8;
  wl[tid] = (j < nb * 8) ? ((e << 6) | j) : -1;
}

// O[e][n][k] = bf16( W[e][k][n] + 2 * sum_r A[e][k][r]*Bm[e][r][n] )
// 64(k) x 32(n) tile; float4 loads, short8 stores (16B/lane).
__global__ void k_wprep(const float* __restrict__ W, const float* __restrict__ A,
                        const float* __restrict__ Bm, short* __restrict__ O,
                        int Kd, int Nd) {
  const int e = blockIdx.z;
  const float* We = W + (size_t)e * Kd * Nd;
  const float* Ae = A + (size_t)e * Kd * 8;
  const float* Be = Bm + (size_t)e * 8 * Nd;
  short* Oe = O + (size_t)e * Kd * Nd;
  __shared__ float tile[64][33];
  __shared__ float As[64][9];
  __shared__ float Bs[8][32];
  const int n0 = blockIdx.x * 32, k0 = blockIdx.y * 64;
  {
    const int rr = threadIdx.x >> 3;         // 0..31
    const int cc = (threadIdx.x & 7) * 4;    // 0..28
#pragma unroll
    for (int h = 0; h < 2; h++) {
      float4 v = *(const float4*)(We + (size_t)(k0 + rr + 32 * h) * Nd + n0 + cc);
      tile[rr + 32 * h][cc + 0] = v.x;
      tile[rr + 32 * h][cc + 1] = v.y;
      tile[rr + 32 * h][cc + 2] = v.z;
      tile[rr + 32 * h][cc + 3] = v.w;
    }
  }
  {
    int kk = threadIdx.x >> 3, r = threadIdx.x & 7;
    As[kk][r] = Ae[(size_t)(k0 + kk) * 8 + r];
    As[kk + 32][r] = Ae[(size_t)(k0 + kk + 32) * 8 + r];
  }
  {
    int rr = threadIdx.x >> 5, nn = threadIdx.x & 31;
    Bs[rr][nn] = Be[(size_t)rr * Nd + n0 + nn];
  }
  __syncthreads();
  const int n2 = threadIdx.x >> 3;        // 0..31
  const int kg = (threadIdx.x & 7) * 8;   // 0..56
  float bl[8];
#pragma unroll
  for (int r = 0; r < 8; r++) bl[r] = Bs[r][n2];
  short ov[8];
#pragma unroll
  for (int i = 0; i < 8; i++) {
    const int k = kg + i;
    float v = tile[k][n2];
    float l = 0.f;
#pragma unroll
    for (int r = 0; r < 8; r++) l += As[k][r] * bl[r];
    ov[i] = bf16r(v + 2.0f * l);
  }
  *(bf16x8*)(Oe + (size_t)(n0 + n2) * Kd + k0 + kg) = *(bf16x8*)ov;
}

__global__ void k_xconv(const float* __restrict__ x, short* __restrict__ xb) {
  const int i = (blockIdx.x * 256 + threadIdx.x) * 4;
  float4 v = *(const float4*)(x + i);
  short4 s;
  s.x = bf16r(v.x); s.y = bf16r(v.y); s.z = bf16r(v.z); s.w = bf16r(v.w);
  *(short4*)(xb + i) = s;
}

// ---------------- 256^2 merged-group GEMM ----------------
// Tile 256x256, BK=64, 512 threads = 8 waves (2M x 4N), per-wave C = 128x64.
// LDS: sA/sB each [2 slots][256][64] bf16 = 64KB -> 128KB.
// Swizzle: LDS[row][c16] holds global[row][c16 ^ (row&7)] (16B units).
// Group t (computes K-tile t from slot t&1):
//   burst 24 ds_reads (aLo8,bLo4,bHi4,aHi8; in-order -> compiler emits
//   counted lgkmcnt cascade before MM1/MM2/MM3)
//   early stage: A(t+1) -> slot^1   (4 loads)
//   MM1(aLo,bLo) MM2(aLo,bHi)
//   s_barrier            // all waves' slot-B reads completed (used by MM1/2)
//   late stage: B(t+2) -> slot      (4 loads)
//   MM3(aHi,bLo) MM4(aHi,bHi)
//   s_waitcnt vmcnt(4)   // drains A(t+1),B(t+1); leaves B(t+2) in flight
//   s_barrier
// Hazards: early A-stage targets slot^1-A (all reads of it drained before the
// previous group's end barrier); late B-stage targets slot-B, whose reads
// completed before the mid-barrier (each wave's MM2 consumed bHi first);
// slot-A reads (aHi) have no same-group writer. Steady-state vmem queue
// [B(t+1),A(t+1),B(t+2)] -> vmcnt(4) drains exactly what group t+1 reads.
// Cross-item: vmcnt(0) at item start drains leftover tail loads.

#define MM_S(AARR, BARR, MG, NG) \
  _Pragma("unroll") \
  for (int s_ = 0; s_ < 2; ++s_) \
    _Pragma("unroll") \
    for (int f_ = 0; f_ < 4; ++f_) \
      _Pragma("unroll") \
      for (int g_ = 0; g_ < 2; ++g_) \
        acc[(MG) + f_][(NG) + g_] = __builtin_amdgcn_mfma_f32_16x16x32_bf16( \
            AARR[f_][s_], BARR[g_][s_], acc[(MG) + f_][(NG) + g_], 0, 0, 0);

template <int KDIM, bool GATHER, bool GLU>
__global__ __launch_bounds__(512) void k_gemmG(
    const short* __restrict__ Abuf, const short* __restrict__ Bbuf,
    const float* __restrict__ bias, const int* __restrict__ cnt,
    const int* __restrict__ offs, const int* __restrict__ wl,
    const int* __restrict__ list, short* __restrict__ outbuf) {
  constexpr int KT = KDIM / 64;

  __shared__ __align__(16) short sA[2 * 256 * 64];
  __shared__ __align__(16) short sB[2 * 256 * 64];
  constexpr int SLOT = 256 * 64;   // 16384 shorts
  constexpr int HALF = 128 * 64;   // 8192 shorts

  const int tid = threadIdx.x;
  const int lane = tid & 63;
  const int wv = tid >> 6;   // 0..7
  const int wr = wv >> 2;    // 0..1
  const int wc = wv & 3;     // 0..3
  const int lm = lane & 15;
  const int quad = lane >> 4;

  const int srow = tid >> 3;                        // 0..63
  const int scol = ((tid & 7) ^ (srow & 7)) * 8;    // 16B-unit swizzle

  const int rbA = (wr * 128 + lm) * 64;
  const int rbB = (wc * 64 + lm) * 64;
  const int c0 = ((0 + quad) ^ (lane & 7)) * 8;
  const int c1 = ((4 + quad) ^ (lane & 7)) * 8;

  for (int item = blockIdx.x; item < 512; item += 256) {
    const int wit = wl[item];
    if (wit < 0) continue;
    const int e = wit >> 6;
    const int m0 = ((wit >> 3) & 7) * 256;
    const int n0 = (wit & 7) * 256;
    const int M = cnt[e];
    const int off_e = offs[e];
    const short* Bp = Bbuf + (size_t)e * 2048 * KDIM;

    uint32_t offA[4], offB[4];
#pragma unroll
    for (int j = 0; j < 4; ++j) {
      const int r = m0 + srow + 64 * j;
      const int rc = min(r, M - 1);
      if constexpr (GATHER) {
        offA[j] = (uint32_t)list[e * 2048 + rc] * (uint32_t)KDIM + (uint32_t)scol;
      } else {
        offA[j] = (uint32_t)(off_e + rc) * (uint32_t)KDIM + (uint32_t)scol;
      }
      offB[j] = (uint32_t)(n0 + srow + 64 * j) * (uint32_t)KDIM + (uint32_t)scol;
    }

    auto stageA = [&](int slot, int h, int kt) {
      short* d = sA + slot * SLOT + h * HALF + tid * 8;
      load_lds16(Abuf + offA[2 * h] + kt * 64, d);
      load_lds16(Abuf + offA[2 * h + 1] + kt * 64, d + 4096);
    };
    auto stageB = [&](int slot, int h, int kt) {
      short* d = sB + slot * SLOT + h * HALF + tid * 8;
      load_lds16(Bp + offB[2 * h] + kt * 64, d);
      load_lds16(Bp + offB[2 * h + 1] + kt * 64, d + 4096);
    };

    auto rdA = [&](int slot, int mg, bf16x8 (&a)[4][2]) {
#pragma unroll
      for (int f = 0; f < 4; ++f) {
        const short* p = sA + slot * SLOT + rbA + (mg + f) * 1024;
        a[f][0] = *(const bf16x8*)(p + c0);
        a[f][1] = *(const bf16x8*)(p + c1);
      }
    };
    auto rdB = [&](int slot, int ng, bf16x8 (&b)[2][2]) {
#pragma unroll
      for (int g = 0; g < 2; ++g) {
        const short* p = sB + slot * SLOT + rbB + (ng + g) * 1024;
        b[g][0] = *(const bf16x8*)(p + c0);
        b[g][1] = *(const bf16x8*)(p + c1);
      }
    };

    f32x4 acc[8][4];
#pragma unroll
    for (int i = 0; i < 8; ++i)
#pragma unroll
      for (int j = 0; j < 4; ++j) acc[i][j] = (f32x4){0.f, 0.f, 0.f, 0.f};

    // drain this wave's leftover tail loads (same LDS dests as new prologue)
    asm volatile("s_waitcnt vmcnt(0)" ::: "memory");

    // ---- prologue: A0,B0 -> slot0; B1 -> slot1 ----
    stageA(0, 0, 0); stageA(0, 1, 0);
    stageB(0, 0, 0); stageB(0, 1, 0);
    {
      const int k1 = (KT > 1) ? 1 : 0;
      stageB(1, 0, k1); stageB(1, 1, k1);
    }
    asm volatile("s_waitcnt vmcnt(4)" ::: "memory");
    asm volatile("s_barrier" ::: "memory");

    bf16x8 aLo[4][2], aHi[4][2], bLo[2][2], bHi[2][2];

#pragma unroll 1
    for (int t = 0; t < KT; ++t) {
      const int slot = t & 1;
      const int tA = min(t + 1, KT - 1);
      const int tB = min(t + 2, KT - 1);
      // burst reads (in order: aLo, bLo, bHi, aHi)
      rdA(slot, 0, aLo);
      rdB(slot, 0, bLo);
      rdB(slot, 2, bHi);
      rdA(slot, 4, aHi);
      // early stage: next tile's A into other slot
      stageA(slot ^ 1, 0, tA); stageA(slot ^ 1, 1, tA);
      __builtin_amdgcn_s_setprio(1);
      MM_S(aLo, bLo, 0, 0);
      MM_S(aLo, bHi, 0, 2);
      __builtin_amdgcn_s_setprio(0);
      asm volatile("s_barrier" ::: "memory");  // all slot-B reads complete
      // late stage: tile t+2's B into current slot
      stageB(slot, 0, tB); stageB(slot, 1, tB);
      __builtin_amdgcn_s_setprio(1);
      MM_S(aHi, bLo, 4, 0);
      MM_S(aHi, bHi, 4, 2);
      __builtin_amdgcn_s_setprio(0);
      asm volatile("s_waitcnt vmcnt(4)" ::: "memory");  // A(t+1),B(t+1) landed
      asm volatile("s_barrier" ::: "memory");
    }

    // ---- epilogue ----
    if constexpr (GLU) {
      const float* be = bias + e * 2048;
#pragma unroll
      for (int m = 0; m < 8; ++m) {
        const int rbase = m0 + wr * 128 + m * 16 + quad * 4;
#pragma unroll
        for (int g = 0; g < 4; ++g) {
          const int col = n0 + wc * 64 + g * 16 + lm;  // parity == lane parity
          const float bb = be[col];
#pragma unroll
          for (int r = 0; r < 4; ++r) {
            const int slot = rbase + r;
            float val = acc[m][g][r] + bb;
            float other = __shfl_xor(val, 1);
            if (((lane & 1) == 0) && (slot < M)) {
              float gt = fminf(val, 7.f);
              float u = fminf(fmaxf(other, -7.f), 7.f);
              float glu = gt / (1.f + __expf(-1.702f * gt));
              outbuf[(size_t)(off_e + slot) * 1024 + (col >> 1)] = bf16r((u + 1.f) * glu);
            }
          }
        }
      }
    } else {
#pragma unroll
      for (int m = 0; m < 8; ++m) {
#pragma unroll
        for (int r = 0; r < 4; ++r) {
          const int slot = m0 + wr * 128 + m * 16 + quad * 4 + r;
          if (slot >= M) continue;
          short* prow = outbuf + (size_t)(off_e + slot) * 2048;
#pragma unroll
          for (int g = 0; g < 4; ++g) {
            const int h = n0 + wc * 64 + g * 16 + lm;
            prow[h] = bf16r(acc[m][g][r]);
          }
        }
      }
    }
  }
}

// out[t,h] = sum_j wt_j * (pairbuf[pair_j][h] + b2[e_j][h])
__global__ __launch_bounds__(256) void k_combine(
    const short* __restrict__ pairbuf, const float* __restrict__ bias2,
    const float* __restrict__ wbuf, const int* __restrict__ offs,
    const int* __restrict__ tok_nh, const int* __restrict__ tok_pair,
    float* __restrict__ out) {
  const int t = blockIdx.x;
  const int h0 = threadIdx.x * 8;
  const int nh = tok_nh[t];
  float acc[8];
#pragma unroll
  for (int i = 0; i < 8; i++) acc[i] = 0.f;
  for (int j = 0; j < nh; j++) {
    const int p = tok_pair[t * 4 + j];
    const int e = p >> 16, slot = p & 0xffff;
    const float wt = wbuf[e * 2048 + t];
    const bf16x8 v = *(const bf16x8*)(pairbuf + (size_t)(offs[e] + slot) * 2048 + h0);
    const float4 bA = *(const float4*)(bias2 + e * 2048 + h0);
    const float4 bB = *(const float4*)(bias2 + e * 2048 + h0 + 4);
    acc[0] += wt * (bf16f(v[0]) + bA.x);
    acc[1] += wt * (bf16f(v[1]) + bA.y);
    acc[2] += wt * (bf16f(v[2]) + bA.z);
    acc[3] += wt * (bf16f(v[3]) + bA.w);
    acc[4] += wt * (bf16f(v[4]) + bB.x);
    acc[5] += wt * (bf16f(v[5]) + bB.y);
    acc[6] += wt * (bf16f(v[6]) + bB.z);
    acc[7] += wt * (bf16f(v[7]) + bB.w);
  }
  float4 oA = {acc[0], acc[1], acc[2], acc[3]};
  float4 oB = {acc[4], acc[5], acc[6], acc[7]};
  *(float4*)(out + (size_t)t * 2048 + h0) = oA;
  *(float4*)(out + (size_t)t * 2048 + h0 + 4) = oB;
}

extern "C" void kernel_launch(void* const* d_in, const int* in_sizes, int n_in,
                              void* d_out, int out_size, void* d_ws, size_t ws_size,
                              hipStream_t stream) {
  const float* x   = (const float*)d_in[0];
  const float* rw  = (const float*)d_in[1];
  const float* w1  = (const float*)d_in[2];
  const float* b1  = (const float*)d_in[3];
  const float* w2  = (const float*)d_in[4];
  const float* b2  = (const float*)d_in[5];
  const float* a1  = (const float*)d_in[6];
  const float* lb1 = (const float*)d_in[7];
  const float* a2  = (const float*)d_in[8];
  const float* lb2 = (const float*)d_in[9];
  const int* idx   = (const int*)d_in[10];
  float* out = (float*)d_out;

  char* ws = (char*)d_ws;
  int* cnt     = (int*)(ws);
  int* offs    = (int*)(ws + 64);
  int* tok_nh  = (int*)(ws + 128);           // 8 KB
  int* wl      = (int*)(ws + 8320);          // 2 KB worklist (512 ints)
  float* wbuf  = (float*)(ws + 16384);       // 64 KB
  int* list    = (int*)(ws + 81920);         // 64 KB
  int* tok_pair= (int*)(ws + 147456);        // 32 KB
  short* Xb    = (short*)(ws + (1ull << 20));        // 8 MB
  short* gated = (short*)(ws + 9437184ull);          // 16 MB
  short* W2T   = (short*)(ws + 26214400ull);         // 32 MB
  short* W1T   = (short*)(ws + 59768832ull);         // 64 MB
  short* pairbuf = (short*)(ws + 59768832ull);       // ALIASES W1T (dead after gemm1)

  hipMemsetAsync(cnt, 0, 64, stream);

  k_route<<<dim3(8), dim3(256), 0, stream>>>(idx, rw, wbuf, cnt, list, tok_nh, tok_pair);
  k_prefix<<<dim3(1), dim3(512), 0, stream>>>(cnt, offs, wl);
  k_wprep<<<dim3(64, 32, 8), dim3(256), 0, stream>>>(w1, a1, lb1, W1T, 2048, 2048);
  k_wprep<<<dim3(64, 16, 8), dim3(256), 0, stream>>>(w2, a2, lb2, W2T, 1024, 2048);
  k_xconv<<<dim3(4096), dim3(256), 0, stream>>>(x, Xb);
  k_gemmG<2048, true, true><<<dim3(256), dim3(512), 0, stream>>>(
      Xb, W1T, b1, cnt, offs, wl, list, gated);
  k_gemmG<1024, false, false><<<dim3(256), dim3(512), 0, stream>>>(
      gated, W2T, nullptr, cnt, offs, wl, nullptr, pairbuf);
  k_combine<<<dim3(2048), dim3(256), 0, stream>>>(pairbuf, b2, wbuf, offs, tok_nh, tok_pair, out);
}

// Round 5
// 410.946 us; speedup vs baseline: 1.0709x; 1.0135x over previous
//
#include <hip/hip_runtime.h>
#include <stdint.h>

// ExpertLoRA: E=8,H=2048,D=2048,F=1024,T=2048,K=4,R=8, SCALING=2, LIMIT=7, alpha=1.702
// Pipeline:
//  k_route   : w[E][T], per-expert token lists (LDS-counter based, 1 global atomic
//              per block-expert), per-token (e,slot) hit list
//  k_prefix  : prefix sums + FIXED-LAYOUT worklist wl[j*8+e] (dead=-1)
//  k_wprep   : W1eff^T=(W1+2*A1@B1)^T -> bf16 [E][D][H]; W2eff^T [E][H][F]
//  k_xconv   : X fp32 -> bf16 [T][H]
//  k_g1/k_g2 : 256^2 MFMA GEMM, merged group per K-tile (BK=64), sA 2-slot +
//              sB 3-slot (160 KB LDS) -> ONE barrier per K-tile. vmcnt(4) gate.
//  k_combine : out[t,h] = sum_j wt_j * (pairbuf[pair_j][h] + b2[e_j][h])
// ws layout: pairbuf ALIASES W1T (dead after gemm1).

typedef short bf16x8 __attribute__((ext_vector_type(8)));
typedef float f32x4 __attribute__((ext_vector_type(4)));

__device__ __forceinline__ short bf16r(float f) {
  uint32_t u = __float_as_uint(f);
  u += 0x7fffu + ((u >> 16) & 1u);
  return (short)(u >> 16);
}

__device__ __forceinline__ float bf16f(short s) {
  uint32_t u = ((uint32_t)(uint16_t)s) << 16;
  return __uint_as_float(u);
}

__device__ __forceinline__ void load_lds16(const void* g, void* l) {
  __builtin_amdgcn_global_load_lds((const __attribute__((address_space(1))) void*)g,
                                   (__attribute__((address_space(3))) void*)l,
                                   16, 0, 0);
}

// grid 8 x 256. LDS counters -> one global atomicAdd per (block,expert).
__global__ void k_route(const int* __restrict__ idx_raw, const float* __restrict__ rw,
                        float* __restrict__ w, int* __restrict__ cnt, int* __restrict__ list,
                        int* __restrict__ tok_nh, int* __restrict__ tok_pair) {
  __shared__ int s_nz;
  __shared__ int lcnt[8];
  __shared__ int lbase[8];
  const int tid = threadIdx.x;
  if (tid == 0) s_nz = 0;
  if (tid < 8) lcnt[tid] = 0;
  __syncthreads();
  int found = 0;
  for (int i = tid; i < 4096; i += 256) found |= idx_raw[2 * i + 1];
  if (found) atomicOr(&s_nz, 1);
  __syncthreads();
  const bool is64 = (s_nz == 0);

  const int t = blockIdx.x * 256 + tid;
  int ek[4]; float rk[4];
#pragma unroll
  for (int k = 0; k < 4; k++) {
    ek[k] = is64 ? idx_raw[2 * (t * 4 + k)] : idx_raw[t * 4 + k];
    rk[k] = rw[t * 4 + k];
  }
  int le[4], ls[4];
  int j = 0;
#pragma unroll
  for (int e = 0; e < 8; e++) {
    float s = 0.f;
#pragma unroll
    for (int k = 0; k < 4; k++) s += (ek[k] == e) ? rk[k] : 0.f;
    w[e * 2048 + t] = s;
    if (s != 0.f) {
      le[j] = e;
      ls[j] = atomicAdd(&lcnt[e], 1);
      j++;
    }
  }
  __syncthreads();
  if (tid < 8) lbase[tid] = atomicAdd(&cnt[tid], lcnt[tid]);
  __syncthreads();
  for (int i = 0; i < j; i++) {
    const int e = le[i];
    const int slot = lbase[e] + ls[i];
    list[e * 2048 + slot] = t;
    tok_pair[t * 4 + i] = (e << 16) | slot;
  }
  tok_nh[t] = j;
}

// offs[0..8]: prefix sums. wl: FIXED 512 slots, wl[j*8+e] = (e<<6)|j if live
// (j < nb_e*8) else -1. Common case (all nb_e=4): slots 0..255 live.
__global__ void k_prefix(const int* __restrict__ cnt, int* __restrict__ offs,
                         int* __restrict__ wl) {
  const int tid = threadIdx.x;  // 512
  __shared__ int sc[8];
  if (tid < 8) sc[tid] = cnt[tid];
  __syncthreads();
  if (tid == 0) {
    int s = 0;
    for (int e = 0; e < 8; e++) { offs[e] = s; s += sc[e]; }
    offs[8] = s;
  }
  const int j = tid >> 3, e = tid & 7;
  const int nb = (sc[e] + 255) >> 8;
  wl[tid] = (j < nb * 8) ? ((e << 6) | j) : -1;
}

// O[e][n][k] = bf16( W[e][k][n] + 2 * sum_r A[e][k][r]*Bm[e][r][n] )
// 64(k) x 32(n) tile; float4 loads, short8 stores (16B/lane).
__global__ void k_wprep(const float* __restrict__ W, const float* __restrict__ A,
                        const float* __restrict__ Bm, short* __restrict__ O,
                        int Kd, int Nd) {
  const int e = blockIdx.z;
  const float* We = W + (size_t)e * Kd * Nd;
  const float* Ae = A + (size_t)e * Kd * 8;
  const float* Be = Bm + (size_t)e * 8 * Nd;
  short* Oe = O + (size_t)e * Kd * Nd;
  __shared__ float tile[64][33];
  __shared__ float As[64][9];
  __shared__ float Bs[8][32];
  const int n0 = blockIdx.x * 32, k0 = blockIdx.y * 64;
  {
    const int rr = threadIdx.x >> 3;         // 0..31
    const int cc = (threadIdx.x & 7) * 4;    // 0..28
#pragma unroll
    for (int h = 0; h < 2; h++) {
      float4 v = *(const float4*)(We + (size_t)(k0 + rr + 32 * h) * Nd + n0 + cc);
      tile[rr + 32 * h][cc + 0] = v.x;
      tile[rr + 32 * h][cc + 1] = v.y;
      tile[rr + 32 * h][cc + 2] = v.z;
      tile[rr + 32 * h][cc + 3] = v.w;
    }
  }
  {
    int kk = threadIdx.x >> 3, r = threadIdx.x & 7;
    As[kk][r] = Ae[(size_t)(k0 + kk) * 8 + r];
    As[kk + 32][r] = Ae[(size_t)(k0 + kk + 32) * 8 + r];
  }
  {
    int rr = threadIdx.x >> 5, nn = threadIdx.x & 31;
    Bs[rr][nn] = Be[(size_t)rr * Nd + n0 + nn];
  }
  __syncthreads();
  const int n2 = threadIdx.x >> 3;        // 0..31
  const int kg = (threadIdx.x & 7) * 8;   // 0..56
  float bl[8];
#pragma unroll
  for (int r = 0; r < 8; r++) bl[r] = Bs[r][n2];
  short ov[8];
#pragma unroll
  for (int i = 0; i < 8; i++) {
    const int k = kg + i;
    float v = tile[k][n2];
    float l = 0.f;
#pragma unroll
    for (int r = 0; r < 8; r++) l += As[k][r] * bl[r];
    ov[i] = bf16r(v + 2.0f * l);
  }
  *(bf16x8*)(Oe + (size_t)(n0 + n2) * Kd + k0 + kg) = *(bf16x8*)ov;
}

__global__ void k_xconv(const float* __restrict__ x, short* __restrict__ xb) {
  const int i = (blockIdx.x * 256 + threadIdx.x) * 4;
  float4 v = *(const float4*)(x + i);
  short4 s;
  s.x = bf16r(v.x); s.y = bf16r(v.y); s.z = bf16r(v.z); s.w = bf16r(v.w);
  *(short4*)(xb + i) = s;
}

// ---------------- 256^2 single-barrier-per-group GEMM ----------------
// Tile 256x256, BK=64, 512 threads = 8 waves (2M x 4N), per-wave C = 128x64.
// LDS: sA [2][256][64] (64KB) + sB [3][256][64] (96KB) = 160KB (CU max).
// Swizzle: LDS[row][c16] holds global[row][c16 ^ (row&7)] (16B units).
// Group t (reads A-slot t&1, B-slot t%3):
//   24 ds_reads -> compiler-counted lgkm cascade into 64 MFMA
//   stage A(t+1) -> sA[(t+1)&1]   (4 loads; slot's group-(t-1) reads done)
//   stage B(t+2) -> sB[(t+2)%3]   (4 loads; slot's group-(t-1) reads done)
//   setprio(1) MFMA setprio(0)
//   s_waitcnt vmcnt(4)   // A(t+1),B(t+1) landed; B(t+2) stays in flight
//   s_waitcnt lgkmcnt(0) // no outstanding ds_read crosses the barrier
//   s_barrier            // the ONLY barrier per group
// vmem queue at gate: [B(t+1), A(t+1), B(t+2)] -> vmcnt(4) drains first two.
// No stage targets a slot read in the same group -> mid-barrier eliminated.
// Cross-item: vmcnt(0) at item start drains leftover tail loads.

#define MM_S(AARR, BARR, MG, NG) \
  _Pragma("unroll") \
  for (int s_ = 0; s_ < 2; ++s_) \
    _Pragma("unroll") \
    for (int f_ = 0; f_ < 4; ++f_) \
      _Pragma("unroll") \
      for (int g_ = 0; g_ < 2; ++g_) \
        acc[(MG) + f_][(NG) + g_] = __builtin_amdgcn_mfma_f32_16x16x32_bf16( \
            AARR[f_][s_], BARR[g_][s_], acc[(MG) + f_][(NG) + g_], 0, 0, 0);

template <int KDIM, bool GATHER, bool GLU>
__device__ __forceinline__ void gemm_body(
    const short* __restrict__ Abuf, const short* __restrict__ Bbuf,
    const float* __restrict__ bias, const int* __restrict__ cnt,
    const int* __restrict__ offs, const int* __restrict__ wl,
    const int* __restrict__ list, short* __restrict__ outbuf) {
  constexpr int KT = KDIM / 64;

  __shared__ __align__(16) short sA[2 * 256 * 64];  // 64 KB
  __shared__ __align__(16) short sB[3 * 256 * 64];  // 96 KB
  constexpr int SLOT = 256 * 64;   // 16384 shorts = 32 KB
  constexpr int HALF = 128 * 64;   // 8192 shorts

  const int tid = threadIdx.x;
  const int lane = tid & 63;
  const int wv = tid >> 6;   // 0..7
  const int wr = wv >> 2;    // 0..1
  const int wc = wv & 3;     // 0..3
  const int lm = lane & 15;
  const int quad = lane >> 4;

  const int srow = tid >> 3;                        // 0..63
  const int scol = ((tid & 7) ^ (srow & 7)) * 8;    // 16B-unit swizzle

  const int rbA = (wr * 128 + lm) * 64;
  const int rbB = (wc * 64 + lm) * 64;
  const int c0 = ((0 + quad) ^ (lane & 7)) * 8;
  const int c1 = ((4 + quad) ^ (lane & 7)) * 8;

  for (int item = blockIdx.x; item < 512; item += 256) {
    const int wit = wl[item];
    if (wit < 0) continue;
    const int e = wit >> 6;
    const int m0 = ((wit >> 3) & 7) * 256;
    const int n0 = (wit & 7) * 256;
    const int M = cnt[e];
    const int off_e = offs[e];
    const short* Bp = Bbuf + (size_t)e * 2048 * KDIM;

    uint32_t offA[4], offB[4];
#pragma unroll
    for (int j = 0; j < 4; ++j) {
      const int r = m0 + srow + 64 * j;
      const int rc = min(r, M - 1);
      if constexpr (GATHER) {
        offA[j] = (uint32_t)list[e * 2048 + rc] * (uint32_t)KDIM + (uint32_t)scol;
      } else {
        offA[j] = (uint32_t)(off_e + rc) * (uint32_t)KDIM + (uint32_t)scol;
      }
      offB[j] = (uint32_t)(n0 + srow + 64 * j) * (uint32_t)KDIM + (uint32_t)scol;
    }

    auto stageA2 = [&](short* base, int kt) {
      short* d = base + tid * 8;
      load_lds16(Abuf + offA[0] + kt * 64, d);
      load_lds16(Abuf + offA[1] + kt * 64, d + 4096);
      load_lds16(Abuf + offA[2] + kt * 64, d + HALF);
      load_lds16(Abuf + offA[3] + kt * 64, d + HALF + 4096);
    };
    auto stageB2 = [&](short* base, int kt) {
      short* d = base + tid * 8;
      load_lds16(Bp + offB[0] + kt * 64, d);
      load_lds16(Bp + offB[1] + kt * 64, d + 4096);
      load_lds16(Bp + offB[2] + kt * 64, d + HALF);
      load_lds16(Bp + offB[3] + kt * 64, d + HALF + 4096);
    };

    auto rdA = [&](const short* base, int mg, bf16x8 (&a)[4][2]) {
#pragma unroll
      for (int f = 0; f < 4; ++f) {
        const short* p = base + rbA + (mg + f) * 1024;
        a[f][0] = *(const bf16x8*)(p + c0);
        a[f][1] = *(const bf16x8*)(p + c1);
      }
    };
    auto rdB = [&](const short* base, int ng, bf16x8 (&b)[2][2]) {
#pragma unroll
      for (int g = 0; g < 2; ++g) {
        const short* p = base + rbB + (ng + g) * 1024;
        b[g][0] = *(const bf16x8*)(p + c0);
        b[g][1] = *(const bf16x8*)(p + c1);
      }
    };

    f32x4 acc[8][4];
#pragma unroll
    for (int i = 0; i < 8; ++i)
#pragma unroll
      for (int j = 0; j < 4; ++j) acc[i][j] = (f32x4){0.f, 0.f, 0.f, 0.f};

    // drain this wave's leftover tail loads (same LDS dests as new prologue)
    asm volatile("s_waitcnt vmcnt(0)" ::: "memory");

    // ---- prologue: A0->sA0, B0->sB0, B1->sB1 ----
    stageA2(sA, 0);
    stageB2(sB, 0);
    stageB2(sB + SLOT, (KT > 1) ? 1 : 0);
    asm volatile("s_waitcnt vmcnt(4)" ::: "memory");
    asm volatile("s_barrier" ::: "memory");

    bf16x8 aLo[4][2], aHi[4][2], bLo[2][2], bHi[2][2];
    int sbr = 0, sbw = 2;

#pragma unroll 1
    for (int t = 0; t < KT; ++t) {
      const int s = t & 1;
      const short* sAr = sA + s * SLOT;
      short* sAw = sA + (s ^ 1) * SLOT;
      const short* sBr = sB + sbr * SLOT;
      short* sBw = sB + sbw * SLOT;
      const int tA = min(t + 1, KT - 1);
      const int tB = min(t + 2, KT - 1);
      // burst reads (in order: aLo, bLo, bHi, aHi)
      rdA(sAr, 0, aLo);
      rdB(sBr, 0, bLo);
      rdB(sBr, 2, bHi);
      rdA(sAr, 4, aHi);
      // stages (no slot conflicts within the group)
      stageA2(sAw, tA);
      stageB2(sBw, tB);
      __builtin_amdgcn_s_setprio(1);
      MM_S(aLo, bLo, 0, 0);
      MM_S(aLo, bHi, 0, 2);
      MM_S(aHi, bLo, 4, 0);
      MM_S(aHi, bHi, 4, 2);
      __builtin_amdgcn_s_setprio(0);
      asm volatile("s_waitcnt vmcnt(4)" ::: "memory");   // A(t+1),B(t+1) landed
      asm volatile("s_waitcnt lgkmcnt(0)" ::: "memory"); // reads drained
      asm volatile("s_barrier" ::: "memory");
      sbr = (sbr == 2) ? 0 : sbr + 1;
      sbw = (sbw == 2) ? 0 : sbw + 1;
    }

    // ---- epilogue ----
    if constexpr (GLU) {
      const float* be = bias + e * 2048;
#pragma unroll
      for (int m = 0; m < 8; ++m) {
        const int rbase = m0 + wr * 128 + m * 16 + quad * 4;
#pragma unroll
        for (int g = 0; g < 4; ++g) {
          const int col = n0 + wc * 64 + g * 16 + lm;  // parity == lane parity
          const float bb = be[col];
#pragma unroll
          for (int r = 0; r < 4; ++r) {
            const int slot = rbase + r;
            float val = acc[m][g][r] + bb;
            float other = __shfl_xor(val, 1);
            if (((lane & 1) == 0) && (slot < M)) {
              float gt = fminf(val, 7.f);
              float u = fminf(fmaxf(other, -7.f), 7.f);
              float glu = gt / (1.f + __expf(-1.702f * gt));
              outbuf[(size_t)(off_e + slot) * 1024 + (col >> 1)] = bf16r((u + 1.f) * glu);
            }
          }
        }
      }
    } else {
#pragma unroll
      for (int m = 0; m < 8; ++m) {
#pragma unroll
        for (int r = 0; r < 4; ++r) {
          const int slot = m0 + wr * 128 + m * 16 + quad * 4 + r;
          if (slot >= M) continue;
          short* prow = outbuf + (size_t)(off_e + slot) * 2048;
#pragma unroll
          for (int g = 0; g < 4; ++g) {
            const int h = n0 + wc * 64 + g * 16 + lm;
            prow[h] = bf16r(acc[m][g][r]);
          }
        }
      }
    }
  }
}

__global__ __launch_bounds__(512) void k_g1(
    const short* __restrict__ Abuf, const short* __restrict__ Bbuf,
    const float* __restrict__ bias, const int* __restrict__ cnt,
    const int* __restrict__ offs, const int* __restrict__ wl,
    const int* __restrict__ list, short* __restrict__ outbuf) {
  gemm_body<2048, true, true>(Abuf, Bbuf, bias, cnt, offs, wl, list, outbuf);
}

__global__ __launch_bounds__(512) void k_g2(
    const short* __restrict__ Abuf, const short* __restrict__ Bbuf,
    const int* __restrict__ cnt, const int* __restrict__ offs,
    const int* __restrict__ wl, short* __restrict__ outbuf) {
  gemm_body<1024, false, false>(Abuf, Bbuf, nullptr, cnt, offs, wl, nullptr, outbuf);
}

// out[t,h] = sum_j wt_j * (pairbuf[pair_j][h] + b2[e_j][h])
__global__ __launch_bounds__(256) void k_combine(
    const short* __restrict__ pairbuf, const float* __restrict__ bias2,
    const float* __restrict__ wbuf, const int* __restrict__ offs,
    const int* __restrict__ tok_nh, const int* __restrict__ tok_pair,
    float* __restrict__ out) {
  const int t = blockIdx.x;
  const int h0 = threadIdx.x * 8;
  const int nh = tok_nh[t];
  float acc[8];
#pragma unroll
  for (int i = 0; i < 8; i++) acc[i] = 0.f;
  for (int j = 0; j < nh; j++) {
    const int p = tok_pair[t * 4 + j];
    const int e = p >> 16, slot = p & 0xffff;
    const float wt = wbuf[e * 2048 + t];
    const bf16x8 v = *(const bf16x8*)(pairbuf + (size_t)(offs[e] + slot) * 2048 + h0);
    const float4 bA = *(const float4*)(bias2 + e * 2048 + h0);
    const float4 bB = *(const float4*)(bias2 + e * 2048 + h0 + 4);
    acc[0] += wt * (bf16f(v[0]) + bA.x);
    acc[1] += wt * (bf16f(v[1]) + bA.y);
    acc[2] += wt * (bf16f(v[2]) + bA.z);
    acc[3] += wt * (bf16f(v[3]) + bA.w);
    acc[4] += wt * (bf16f(v[4]) + bB.x);
    acc[5] += wt * (bf16f(v[5]) + bB.y);
    acc[6] += wt * (bf16f(v[6]) + bB.z);
    acc[7] += wt * (bf16f(v[7]) + bB.w);
  }
  float4 oA = {acc[0], acc[1], acc[2], acc[3]};
  float4 oB = {acc[4], acc[5], acc[6], acc[7]};
  *(float4*)(out + (size_t)t * 2048 + h0) = oA;
  *(float4*)(out + (size_t)t * 2048 + h0 + 4) = oB;
}

extern "C" void kernel_launch(void* const* d_in, const int* in_sizes, int n_in,
                              void* d_out, int out_size, void* d_ws, size_t ws_size,
                              hipStream_t stream) {
  const float* x   = (const float*)d_in[0];
  const float* rw  = (const float*)d_in[1];
  const float* w1  = (const float*)d_in[2];
  const float* b1  = (const float*)d_in[3];
  const float* w2  = (const float*)d_in[4];
  const float* b2  = (const float*)d_in[5];
  const float* a1  = (const float*)d_in[6];
  const float* lb1 = (const float*)d_in[7];
  const float* a2  = (const float*)d_in[8];
  const float* lb2 = (const float*)d_in[9];
  const int* idx   = (const int*)d_in[10];
  float* out = (float*)d_out;

  char* ws = (char*)d_ws;
  int* cnt     = (int*)(ws);
  int* offs    = (int*)(ws + 64);
  int* tok_nh  = (int*)(ws + 128);           // 8 KB
  int* wl      = (int*)(ws + 8320);          // 2 KB worklist (512 ints)
  float* wbuf  = (float*)(ws + 16384);       // 64 KB
  int* list    = (int*)(ws + 81920);         // 64 KB
  int* tok_pair= (int*)(ws + 147456);        // 32 KB
  short* Xb    = (short*)(ws + (1ull << 20));        // 8 MB
  short* gated = (short*)(ws + 9437184ull);          // 16 MB
  short* W2T   = (short*)(ws + 26214400ull);         // 32 MB
  short* W1T   = (short*)(ws + 59768832ull);         // 64 MB
  short* pairbuf = (short*)(ws + 59768832ull);       // ALIASES W1T (dead after gemm1)

  hipMemsetAsync(cnt, 0, 64, stream);

  k_route<<<dim3(8), dim3(256), 0, stream>>>(idx, rw, wbuf, cnt, list, tok_nh, tok_pair);
  k_prefix<<<dim3(1), dim3(512), 0, stream>>>(cnt, offs, wl);
  k_wprep<<<dim3(64, 32, 8), dim3(256), 0, stream>>>(w1, a1, lb1, W1T, 2048, 2048);
  k_wprep<<<dim3(64, 16, 8), dim3(256), 0, stream>>>(w2, a2, lb2, W2T, 1024, 2048);
  k_xconv<<<dim3(4096), dim3(256), 0, stream>>>(x, Xb);
  k_g1<<<dim3(256), dim3(512), 0, stream>>>(Xb, W1T, b1, cnt, offs, wl, list, gated);
  k_g2<<<dim3(256), dim3(512), 0, stream>>>(gated, W2T, cnt, offs, wl, pairbuf);
  k_combine<<<dim3(2048), dim3(256), 0, stream>>>(pairbuf, b2, wbuf, offs, tok_nh, tok_pair, out);
}